// Round 10
// baseline (133.278 us; speedup 1.0000x reference)
//
#include <hip/hip_runtime.h>

#define HD 64       // HIDDEN_DIM
#define NE 512      // N_EMBEDS
#define HW 1024     // 32*32 spatial positions per batch image

typedef float f32x2  __attribute__((ext_vector_type(2)));
typedef float f32x4  __attribute__((ext_vector_type(4)));
typedef float f32x16 __attribute__((ext_vector_type(16)));

// ---------------------------------------------------------------------------
// Prep (130 blocks x 256):
//  blk 0..127 : epT[c][k] = -2 * e[k][c]   (transposed, code-major rows)
//  blk 128/129: esq[k] = np.sum(e[k]*e[k]), numpy pairwise-8, no contraction.
//  Verified absmax==0.0 R1-R17.
// ---------------------------------------------------------------------------
__global__ __launch_bounds__(256) void vq_prep_kernel(const float* __restrict__ e,
                                                      float* __restrict__ epT,
                                                      float* __restrict__ esq) {
  const int blk = blockIdx.x;
  if (blk < 128) {
    const int t = blk * 256 + threadIdx.x;     // 0..32767
    const int c = t >> 9, k = t & 511;
    epT[t] = -2.0f * e[k * HD + c];
  } else {
    const int k = (blk - 128) * 256 + threadIdx.x;   // 0..511
    const float4* __restrict__ rowv = reinterpret_cast<const float4*>(e + k * HD);
    float row[HD];
    #pragma unroll
    for (int i = 0; i < 16; ++i) {
      const float4 v = rowv[i];
      row[4 * i + 0] = v.x; row[4 * i + 1] = v.y;
      row[4 * i + 2] = v.z; row[4 * i + 3] = v.w;
    }
    float result;
    {
      #pragma clang fp contract(off)
      float r[8];
      #pragma unroll
      for (int j = 0; j < 8; ++j) r[j] = row[j] * row[j];
      #pragma unroll
      for (int i = 8; i < HD; i += 8) {
        #pragma unroll
        for (int j = 0; j < 8; ++j) r[j] = r[j] + row[i + j] * row[i + j];
      }
      result = ((r[0] + r[1]) + (r[2] + r[3])) + ((r[4] + r[5]) + (r[6] + r[7]));
    }
    esq[k] = result;
  }
}

// ---------------------------------------------------------------------------
// Main R20: 1024 blocks x 1024 threads (16 waves). Block = 64 pos x 512 codes,
// wave wq owns 32 codes [32wq, 32wq+32).
//
// R18/R19 post-mortem: source-level SMEM double-buffering is unsalvageable —
// "+s" ties on a separate wait asm let RA materialize s_mov copies of
// IN-FLIGHT load destinations before the s_waitcnt executes. The loaded
// value must never cross an asm boundary while in flight. R20 reverts to
// the R15-HW-VALIDATED fused pattern: s_load x4 + s_waitcnt lgkmcnt(0) in
// ONE asm block, consumers dataflow-ordered after it.
//
// The lever vs R17 (69.6us, VALUBusy 53%, ~3 waves/SIMD) is OCCUPANCY:
//  - 32 codes/wave -> acc[32]; ~56 live VGPRs; amdgpu_waves_per_eu(8)
//    caps allocation at 64 -> 8 waves/SIMD. Stall cover: 8 x 140cy compute
//    per 2-c group >> ~200cy SMEM wait; 16 waves/block share each epT row
//    so most waits are K$ hits (only the first toucher pays L2).
//  - lane = position; x: ONE coalesced global dword per wave-c.
//  - e on the SCALAR pipe: 4x s_load_dwordx16 (two 128B row slices) +
//    lgkmcnt(0) fused per 2 c's. Inner loop: 32 dense v_fmac_f32
//    (s[e], v[x]) + 2 xsq ops; zero movs, zero LDS, zero barriers.
//
// Bit-exactness: acc[k] = fma(epT_val, x_val, acc[k]) over c ascending
// (IEEE-commutative operand order, chain identical to R15/R17-verified);
// xsq/esq numpy pairwise-8 trees identical (chain j <- c mod 8, c ascending
// within chain); distance (xsq+esq[k])+acc[k] association identical;
// within-lane strict < over ascending codes == first-index-wins; cross-wave
// lexicographic (d,idx) merge (ascending wave == ascending code range) ==
// np.argmin first-occurrence semantics. Grid coverage audited: b=blk>>4,
// win=blk&15, 1024 blocks = 64 images x 16 windows.
// ---------------------------------------------------------------------------
__global__ __launch_bounds__(1024)
__attribute__((amdgpu_waves_per_eu(8)))
void vq_main_kernel(const float* __restrict__ x,
                    const float* __restrict__ epT,
                    const float* __restrict__ esq,
                    const float* __restrict__ e,
                    float* __restrict__ out) {
  __shared__ f32x2 scr[16 * 64];       // 8 KB: per-wave per-pos (d, idx)
  __shared__ int   bcomb[64];

  const int t    = threadIdx.x;
  const int lane = t & 63;                                  // = position
  const int wq   = __builtin_amdgcn_readfirstlane(t >> 6);  // 0..15 code slot

  const int blk = blockIdx.x;          // 1024
  const int b   = blk >> 4;            // image 0..63
  const int win = blk & 15;            // 64-position window 0..15
  const size_t xbase = (size_t)b * (HD * HW) + (size_t)win * 64;

  const float* __restrict__ xw = x + xbase + lane;
  const unsigned long long ebase =
      (unsigned long long)(const void*)epT + (unsigned)wq * 128u;

  float acc[32];                       // -2*cross accumulators (codes)
  #pragma unroll
  for (int k = 0; k < 32; ++k) acc[k] = 0.f;
  float r[8];                          // xsq pairwise-8 chain partials
  #pragma unroll
  for (int j = 0; j < 8; ++j) r[j] = 0.f;

  #pragma unroll 1
  for (int C = 0; C < 64; C += 8) {
    // x for this 8-c block: per-lane coalesced dwords (compiler pipelines)
    float xv[8];
    #pragma unroll
    for (int j = 0; j < 8; ++j) xv[j] = xw[(size_t)(C + j) * HW];

    #pragma unroll
    for (int jj = 0; jj < 4; ++jj) {   // 2 c-rows per fused scalar asm block
      f32x16 ea0, ea1, eb0, eb1;
      const unsigned long long ea =
          ebase + (unsigned)((C + 2 * jj) * (NE * 4));
      asm volatile(
          "s_load_dwordx16 %0, %4, 0\n\t"
          "s_load_dwordx16 %1, %4, 64\n\t"
          "s_load_dwordx16 %2, %4, 0x800\n\t"
          "s_load_dwordx16 %3, %4, 0x840\n\t"
          "s_waitcnt lgkmcnt(0)"
          : "=&s"(ea0), "=&s"(ea1), "=&s"(eb0), "=&s"(eb1)
          : "s"(ea));

      {  // c = C + 2jj
        const float xc = xv[2 * jj];
        {
          #pragma clang fp contract(off)
          const float sq = xc * xc;
          r[2 * jj] = r[2 * jj] + sq;
        }
        #pragma unroll
        for (int k = 0; k < 16; ++k)
          acc[k] = __builtin_fmaf(ea0[k], xc, acc[k]);
        #pragma unroll
        for (int k = 0; k < 16; ++k)
          acc[16 + k] = __builtin_fmaf(ea1[k], xc, acc[16 + k]);
      }
      {  // c = C + 2jj + 1
        const float xc = xv[2 * jj + 1];
        {
          #pragma clang fp contract(off)
          const float sq = xc * xc;
          r[2 * jj + 1] = r[2 * jj + 1] + sq;
        }
        #pragma unroll
        for (int k = 0; k < 16; ++k)
          acc[k] = __builtin_fmaf(eb0[k], xc, acc[k]);
        #pragma unroll
        for (int k = 0; k < 16; ++k)
          acc[16 + k] = __builtin_fmaf(eb1[k], xc, acc[16 + k]);
      }
    }
  }

  // ---- xsq finish: numpy pairwise-8 tree (contract off), per lane
  float xsql;
  {
    #pragma clang fp contract(off)
    xsql = ((r[0] + r[1]) + (r[2] + r[3])) + ((r[4] + r[5]) + (r[6] + r[7]));
  }

  // ---- esq slice for this wave's 32 codes (scalar pipe, fused pattern)
  f32x16 q0, q1;
  {
    const unsigned long long qa =
        (unsigned long long)(const void*)esq + (unsigned)wq * 128u;
    asm volatile(
        "s_load_dwordx16 %0, %2, 0\n\t"
        "s_load_dwordx16 %1, %2, 64\n\t"
        "s_waitcnt lgkmcnt(0)"
        : "=&s"(q0), "=&s"(q1)
        : "s"(qa));
  }

  // ---- per-lane argmin over the wave's 32 codes (ascending: first-wins)
  float bd = __builtin_inff();
  int   bi = 0x7fffffff;
  const int kb = wq * 32;
  #pragma unroll
  for (int k = 0; k < 16; ++k) {
    const float d = (xsql + q0[k]) + acc[k];
    if (d < bd) { bd = d; bi = kb + k; }
  }
  #pragma unroll
  for (int k = 0; k < 16; ++k) {
    const float d = (xsql + q1[k]) + acc[16 + k];
    if (d < bd) { bd = d; bi = kb + 16 + k; }
  }

  scr[wq * 64 + lane] = (f32x2){bd, __int_as_float(bi)};
  __syncthreads();

  // ---- cross-wave merge: ascending wave == ascending code ranges;
  //      lexicographic (d, idx) == np.argmin first-occurrence.
  if (t < 64) {
    f32x2 p = scr[t];
    float bd2 = p[0];
    int   bi2 = __float_as_int(p[1]);
    #pragma unroll
    for (int w2 = 1; w2 < 16; ++w2) {
      const f32x2 pr = scr[w2 * 64 + t];
      const float d = pr[0];
      const int  ix = __float_as_int(pr[1]);
      if (d < bd2 || (d == bd2 && ix < bi2)) { bd2 = d; bi2 = ix; }
    }
    bcomb[t] = bi2;
  }
  __syncthreads();

  // ---- gather winning codebook rows (L2-hot), coalesced stores
  {
    const int pos = t & 63, cg = t >> 6;      // cg 0..15 -> 4 c's each
    const int idx = bcomb[pos];
    const f32x4 ev = *reinterpret_cast<const f32x4*>(e + idx * HD + cg * 4);
    #pragma unroll
    for (int i = 0; i < 4; ++i)
      out[xbase + (size_t)(cg * 4 + i) * HW + pos] = ev[i];
  }
}

extern "C" void kernel_launch(void* const* d_in, const int* in_sizes, int n_in,
                              void* d_out, int out_size, void* d_ws, size_t ws_size,
                              hipStream_t stream) {
  const float* x = (const float*)d_in[0];   // (64, 64, 32, 32) fp32
  const float* e = (const float*)d_in[1];   // (512, 64) fp32
  float* epT = (float*)d_ws;                // 64*512 floats: -2*e transposed
  float* esq = epT + HD * NE;               // 512 floats
  float* out = (float*)d_out;

  vq_prep_kernel<<<130, 256, 0, stream>>>(e, epT, esq);
  vq_main_kernel<<<1024, 1024, 0, stream>>>(x, epT, esq, e, out);
}